// Round 9
// baseline (398.779 us; speedup 1.0000x reference)
//
#include <hip/hip_runtime.h>
#include <hip/hip_bf16.h>
#include <math.h>

typedef __hip_bfloat16 bf16;
typedef __attribute__((ext_vector_type(8))) short bf16x8;
typedef __attribute__((ext_vector_type(4))) float f32x4;

__device__ __forceinline__ float b2f(bf16 x) { return __bfloat162float(x); }
__device__ __forceinline__ float us2f(unsigned short u) {
    return __uint_as_float(((unsigned int)u) << 16);
}
__device__ __forceinline__ unsigned short f2us(float f) {
    bf16 t = __float2bfloat16(f);
    return *reinterpret_cast<unsigned short*>(&t);
}
__device__ __forceinline__ float scrub(float v) {
    return (v == v && fabsf(v) < 3.0e38f) ? v : 0.f;
}
__device__ __forceinline__ float to_float(float x) { return x; }
__device__ __forceinline__ float to_float(bf16 x) { return __bfloat162float(x); }
__device__ __forceinline__ void store_out(float* p, float v) { *p = v; }
__device__ __forceinline__ void store_out(bf16* p, float v) { *p = __float2bfloat16(v); }

// async global->LDS, 16 B per lane; LDS dest = wave-uniform base + lane*16.
__device__ __forceinline__ void cp16(const void* g, void* l) {
    __builtin_amdgcn_global_load_lds(
        (const __attribute__((address_space(1))) unsigned int*)g,
        (__attribute__((address_space(3))) unsigned int*)l, 16, 0, 0);
}

// ---------------------------------------------------------------------------
// Convert all 18 fp32 input tensors into one contiguous bf16 region.
// ---------------------------------------------------------------------------
struct Ptrs { const void* p[18]; };

__constant__ __device__ const long TOFF[19] = {
    0,         2097152,  2098176,  2099200,  6293504,  6301696,  6303744,
    6500352,   6631424,  6633472,  6666240,  6668288,  8765440,  8766464,
    8767488,   10864640, 10866688, 12963840, 12964864};

__global__ __launch_bounds__(256) void convert_kernel(
    Ptrs ptrs, unsigned short* __restrict__ dst)
{
    const long g = (long)blockIdx.x * 256 + threadIdx.x;
    if (g >= 1620608) return;            // 12,964,864 / 8
    const long e0 = g * 8;
    int t = 0;
    #pragma unroll
    for (int i = 1; i < 18; ++i) t += (e0 >= TOFF[i]) ? 1 : 0;
    const long local = e0 - TOFF[t];
    const float4* ps = (const float4*)((const float*)ptrs.p[t] + local);
    const float4 a = ps[0], b = ps[1];
    ushort4 o0, o1;
    o0.x = f2us(a.x); o0.y = f2us(a.y); o0.z = f2us(a.z); o0.w = f2us(a.w);
    o1.x = f2us(b.x); o1.y = f2us(b.y); o1.z = f2us(b.z); o1.w = f2us(b.w);
    *(ushort4*)(dst + e0)     = o0;
    *(ushort4*)(dst + e0 + 4) = o1;
}

// ---------------------------------------------------------------------------
// LayerNorm: one block per row of 1024, 256 threads x 4 elems.
// ---------------------------------------------------------------------------
template <typename TIN>
__global__ __launch_bounds__(256) void ln_kernel(
    const TIN* __restrict__ in, const bf16* __restrict__ gw,
    const bf16* __restrict__ gb, bf16* __restrict__ out)
{
    const int row = blockIdx.x;
    const int tid = threadIdx.x;
    float v[4];
    if constexpr (sizeof(TIN) == 2) {
        ushort4 raw = ((const ushort4*)((const unsigned short*)in + (long)row * 1024))[tid];
        v[0] = us2f(raw.x); v[1] = us2f(raw.y); v[2] = us2f(raw.z); v[3] = us2f(raw.w);
    } else {
        float4 raw = ((const float4*)((const float*)in + (long)row * 1024))[tid];
        v[0] = raw.x; v[1] = raw.y; v[2] = raw.z; v[3] = raw.w;
    }
    float s  = v[0] + v[1] + v[2] + v[3];
    float s2 = v[0]*v[0] + v[1]*v[1] + v[2]*v[2] + v[3]*v[3];
    #pragma unroll
    for (int o = 32; o > 0; o >>= 1) {
        s  += __shfl_xor(s, o);
        s2 += __shfl_xor(s2, o);
    }
    __shared__ float red[8];
    if ((tid & 63) == 0) { red[tid >> 6] = s; red[4 + (tid >> 6)] = s2; }
    __syncthreads();
    s  = red[0] + red[1] + red[2] + red[3];
    s2 = red[4] + red[5] + red[6] + red[7];
    const float mu  = s * (1.f / 1024.f);
    const float var = fmaxf(s2 * (1.f / 1024.f) - mu * mu, 0.f);
    const float rs  = rsqrtf(var + 1e-5f);
    const int c0 = tid * 4;
    ushort4 o;
    o.x = f2us((v[0] - mu) * rs * b2f(gw[c0 + 0]) + b2f(gb[c0 + 0]));
    o.y = f2us((v[1] - mu) * rs * b2f(gw[c0 + 1]) + b2f(gb[c0 + 1]));
    o.z = f2us((v[2] - mu) * rs * b2f(gw[c0 + 2]) + b2f(gb[c0 + 2]));
    o.w = f2us((v[3] - mu) * rs * b2f(gw[c0 + 3]) + b2f(gb[c0 + 3]));
    ((ushort4*)((unsigned short*)out + (long)row * 1024))[tid] = o;
}

// ---------------------------------------------------------------------------
// GEMM (m97-style): C[M,N] = act(A[M,K] @ Bw[N,K]^T + bias) + res.
// ---------------------------------------------------------------------------
template <int BM, int BN, int ACT, bool NG, typename TOUT, typename TRES>
__global__ __launch_bounds__(256) void gemm_as(
    const bf16* __restrict__ A, int lda,
    const bf16* __restrict__ Bw, int ldb,
    TOUT* __restrict__ C, int ldc,
    const bf16* __restrict__ bias,
    const TRES* __restrict__ res,
    int M, int N, int K)
{
    constexpr int AI = BM / 32;
    constexpr int BJ = BN / 32;
    __shared__ __align__(16) short As[BM * 64];
    __shared__ __align__(16) short Bs[BN * 64];
    const int tid  = threadIdx.x;
    const int lane = tid & 63;
    const int wv   = tid >> 6;
    const int m0 = blockIdx.y * BM;
    const int n0 = blockIdx.x * BN;
    const int wm = (wv >> 1) * (BM / 2);
    const int wn = (wv & 1) * (BN / 2);
    const int lr = lane & 15;
    const int lq = lane >> 4;
    const int grow = lane >> 3;
    const int gcol = (lane & 7) * 8;

    if (NG) {
        const int z0 = (N - n0) * 64;
        uint4 z; z.x = z.y = z.z = z.w = 0;
        for (int s = z0 + tid * 8; s < BN * 64; s += 2048)
            *(uint4*)&Bs[s] = z;
    }

    f32x4 acc[AI][BJ] = {};

    for (int k0 = 0; k0 < K; k0 += 64) {
        #pragma unroll
        for (int g = 0; g < BM / 32; ++g) {
            const int gg = g * 4 + wv;
            cp16(A + (long)(m0 + gg * 8 + grow) * lda + k0 + gcol, &As[gg * 512]);
        }
        #pragma unroll
        for (int g = 0; g < BN / 32; ++g) {
            const int gg = g * 4 + wv;
            if (!NG || n0 + gg * 8 < N)
                cp16(Bw + (long)(n0 + gg * 8 + grow) * ldb + k0 + gcol, &Bs[gg * 512]);
        }
        __syncthreads();

        #pragma unroll
        for (int kk = 0; kk < 2; ++kk) {
            bf16x8 af[AI], bfr[BJ];
            #pragma unroll
            for (int i = 0; i < AI; ++i)
                af[i] = *(const bf16x8*)&As[(wm + i * 16 + lr) * 64 + kk * 32 + lq * 8];
            #pragma unroll
            for (int j = 0; j < BJ; ++j)
                bfr[j] = *(const bf16x8*)&Bs[(wn + j * 16 + lr) * 64 + kk * 32 + lq * 8];
            #pragma unroll
            for (int i = 0; i < AI; ++i)
                #pragma unroll
                for (int j = 0; j < BJ; ++j)
                    acc[i][j] = __builtin_amdgcn_mfma_f32_16x16x32_bf16(
                        af[i], bfr[j], acc[i][j], 0, 0, 0);
        }
        __syncthreads();
    }

    #pragma unroll
    for (int j = 0; j < BJ; ++j) {
        const int col = n0 + wn + j * 16 + lr;
        if (col >= N) continue;
        const float bv = bias ? b2f(bias[col]) : 0.f;
        #pragma unroll
        for (int i = 0; i < AI; ++i) {
            const int r0 = m0 + wm + i * 16 + lq * 4;
            #pragma unroll
            for (int r = 0; r < 4; ++r) {
                const long row = r0 + r;
                float v = acc[i][j][r] + bv;
                if (ACT == 1) v = 0.5f * v * (1.f + erff(v * 0.70710678118f));
                if (ACT == 2) v = (v > 20.f) ? v : log1pf(__expf(v));
                if (res) v += to_float(res[row * (long)ldc + col]);
                store_out(&C[row * (long)ldc + col], scrub(v));
            }
        }
    }
}

// ---------------------------------------------------------------------------
// Depthwise causal conv (window 4) + bias + silu, PLUS silu(z) extraction.
// Writes ucz(2048,4096): cols 0-2047 = silu(conv(u)+b), cols 2048-4095 =
// silu(z).  After this kernel xz is fully dead (frees 16 MiB for scan bufs).
// ---------------------------------------------------------------------------
__global__ __launch_bounds__(256) void conv_silu_kernel(
    const bf16* __restrict__ xz, const bf16* __restrict__ cw,
    const bf16* __restrict__ cb, bf16* __restrict__ ucz)
{
    const int gid = blockIdx.x * 256 + threadIdx.x;
    const int d   = gid & 2047;
    const int row = gid >> 11;
    const int t   = row & 1023;
    float acc = b2f(cb[d]);
    #pragma unroll
    for (int j = 0; j < 4; ++j) {
        const int tt = t - 3 + j;
        if (tt >= 0)
            acc += b2f(cw[d * 4 + j]) * b2f(xz[(long)(row - 3 + j) * 4096 + d]);
    }
    ucz[(long)row * 4096 + d] = __float2bfloat16(acc / (1.f + __expf(-acc)));
    const float zz = b2f(xz[(long)row * 4096 + 2048 + d]);
    ucz[(long)row * 4096 + 2048 + d] = __float2bfloat16(zz / (1.f + __expf(-zz)));
}

// ---------------------------------------------------------------------------
// Selective scan: segment-parallel (linear recurrence decomposition).
// h_t = local_t + exp(An*P_t)*h_in,  P_t = within-segment cumsum(dt).
// A) scan_local: 8 segs x 128 steps, grid 2048.  y_local (in-place over
//    delta), P (bf16), h_out.   B) combine.   C) fix.
// ---------------------------------------------------------------------------
__global__ __launch_bounds__(256) void scan_local_kernel(
    const bf16* __restrict__ delta,    // (B*L, 2048)
    const bf16* __restrict__ ucz,      // (B*L, 4096): u | silu(z)
    const bf16* __restrict__ dbc,      // (B*L, 96): dt | B | C
    const float* __restrict__ A_log,   // (2048, 16) fp32
    const float* __restrict__ Dp,      // (2048)     fp32
    bf16* __restrict__ y_local,        // (B*L, 2048) — aliases delta, safe
    bf16* __restrict__ Pbuf,           // (B*L, 2048) cumsum dt (bf16)
    float* __restrict__ h_out)         // (B, 8, 2048, 16)
{
    const int d0  = blockIdx.x * 16;
    const int b   = blockIdx.y;
    const int sg  = blockIdx.z;
    const int tid = threadIdx.x;
    const int n   = tid & 15;
    const int dl  = tid >> 4;
    const int d   = d0 + dl;

    __shared__ float2         sDU[32][16];
    __shared__ float2         sBC[32][16];
    __shared__ float          sZ [32][16];   // silu(z), preloaded
    __shared__ unsigned short sPc[32][16];
    __shared__ unsigned short sY [32][16];
    __shared__ float          sP [32][16][20];

    const float An = -expf(A_log[d * 16 + n]);
    const float Dd = Dp[d];
    float h = 0.f, Pc = 0.f;
    const long rowbase = (long)b * 1024 + sg * 128;

    const int wv  = tid >> 6;
    const int pdl = 4 * wv + ((tid & 63) >> 4);
    const int ptq = tid & 15;

    float rDT[2], rUV[2], rB[2], rC[2], rZ[2];
    auto load_chunk = [&](int t0c) {
        #pragma unroll
        for (int k = 0; k < 2; ++k) {
            const int i  = k * 256 + tid;
            const int tt = i >> 4, dd = i & 15;
            const long r = rowbase + t0c + tt;
            rDT[k] = b2f(delta[r * 2048 + d0 + dd]);
            rUV[k] = b2f(ucz  [r * 4096 + d0 + dd]);
            rB[k]  = b2f(dbc  [r * 96 + 64 + dd]);
            rC[k]  = b2f(dbc  [r * 96 + 80 + dd]);
            rZ[k]  = b2f(ucz  [r * 4096 + 2048 + d0 + dd]);
        }
    };
    auto store_chunk = [&]() {
        #pragma unroll
        for (int k = 0; k < 2; ++k) {
            const int i  = k * 256 + tid;
            const int tt = i >> 4, dd = i & 15;
            sDU[tt][dd] = float2{rDT[k], rUV[k]};
            sBC[tt][dd] = float2{rB[k], rC[k]};
            sZ[tt][dd]  = rZ[k];
        }
    };

    load_chunk(0);
    for (int t0 = 0; t0 < 128; t0 += 32) {
        store_chunk();
        __syncthreads();
        if (t0 + 32 < 128) load_chunk(t0 + 32);

        // ---- phase 2: serial recurrence (no cross-lane) ----
        #pragma unroll 4
        for (int t = 0; t < 32; ++t) {
            const float2 du = sDU[t][dl];
            const float2 bc = sBC[t][n];
            Pc += du.x;
            const float a = __expf(du.x * An);
            h = a * h + (du.x * du.y) * bc.x;
            float p = h * bc.y;
            if (n == 0) { p += du.y * Dd; sPc[t][dl] = f2us(Pc); }
            sP[t][dl][n] = p;
        }

        // ---- phase 3: wave-local n-reduction ----
        #pragma unroll
        for (int k = 0; k < 2; ++k) {
            const int t = ptq + k * 16;
            const float4* pp = (const float4*)&sP[t][pdl][0];
            const float4 p0 = pp[0], p1 = pp[1], p2 = pp[2], p3 = pp[3];
            const float s = ((p0.x + p0.y) + (p0.z + p0.w))
                          + ((p1.x + p1.y) + (p1.z + p1.w))
                          + ((p2.x + p2.y) + (p2.z + p2.w))
                          + ((p3.x + p3.y) + (p3.z + p3.w));
            sY[t][pdl] = f2us(s * sZ[t][pdl]);
        }
        __syncthreads();

        // ---- dump (coalesced) ----
        #pragma unroll
        for (int k = 0; k < 2; ++k) {
            const int i  = k * 256 + tid;
            const int tt = i >> 4, dd = i & 15;
            const long r = rowbase + t0 + tt;
            ((unsigned short*)y_local)[r * 2048 + d0 + dd] = sY[tt][dd];
            ((unsigned short*)Pbuf)  [r * 2048 + d0 + dd] = sPc[tt][dd];
        }
        __syncthreads();
    }

    h_out[((long)(b * 8 + sg) * 2048 + d) * 16 + n] = h;
}

__global__ __launch_bounds__(256) void scan_combine_kernel(
    const bf16*  __restrict__ Pbuf,
    const float* __restrict__ A_log,
    const float* __restrict__ h_out,   // (B, 8, 32768)
    float* __restrict__ h_in)          // (B, 8, 32768)
{
    const int gid = blockIdx.x * 256 + threadIdx.x;   // 65536 = 2*2048*16
    const int b  = gid >> 15;
    const int dn = gid & 32767;
    const int d  = dn >> 4;
    const float An = -expf(A_log[dn]);
    float hin = 0.f;
    h_in[(long)(b * 8) * 32768 + dn] = 0.f;
    for (int s = 0; s < 7; ++s) {
        const float Pend = us2f(((const unsigned short*)Pbuf)
                                [((long)b * 1024 + s * 128 + 127) * 2048 + d]);
        const float hout = h_out[(long)(b * 8 + s) * 32768 + dn];
        hin = hout + __expf(An * Pend) * hin;
        h_in[(long)(b * 8 + s + 1) * 32768 + dn] = hin;
    }
}

__global__ __launch_bounds__(256) void scan_fix_kernel(
    bf16* __restrict__ y,              // y_local -> y (in-place)
    const bf16* __restrict__ Pbuf,
    const bf16* __restrict__ dbc,
    const bf16* __restrict__ ucz,      // silu(z) at cols 2048+
    const float* __restrict__ A_log,
    const float* __restrict__ h_in)    // (B, 8, 32768)
{
    const int d0  = blockIdx.x * 16;
    const int b   = blockIdx.y;
    const int sg  = blockIdx.z;
    const int tid = threadIdx.x;
    const long rowb = (long)b * 1024 + sg * 128;

    __shared__ float sH [16][16];
    __shared__ float sAn[16][16];
    __shared__ float sCc[128][16];

    sH [tid >> 4][tid & 15] = h_in[(long)(b * 8 + sg) * 32768 + d0 * 16 + tid];
    sAn[tid >> 4][tid & 15] = -expf(A_log[d0 * 16 + tid]);
    for (int i = tid; i < 2048; i += 256)
        sCc[i >> 4][i & 15] = b2f(dbc[(rowb + (i >> 4)) * 96 + 80 + (i & 15)]);
    __syncthreads();

    const int dd = tid & 15;
    float4 An4[4], H4[4];
    #pragma unroll
    for (int j = 0; j < 4; ++j) {
        An4[j] = *(const float4*)&sAn[dd][j * 4];
        H4[j]  = *(const float4*)&sH [dd][j * 4];
    }

    #pragma unroll
    for (int k = 0; k < 8; ++k) {
        const int t = k * 16 + (tid >> 4);
        const long row = rowb + t;
        const float P = us2f(((const unsigned short*)Pbuf)[row * 2048 + d0 + dd]);
        float corr = 0.f;
        #pragma unroll
        for (int j = 0; j < 4; ++j) {
            const float4 C4 = *(const float4*)&sCc[t][j * 4];
            corr += C4.x * __expf(An4[j].x * P) * H4[j].x;
            corr += C4.y * __expf(An4[j].y * P) * H4[j].y;
            corr += C4.z * __expf(An4[j].z * P) * H4[j].z;
            corr += C4.w * __expf(An4[j].w * P) * H4[j].w;
        }
        const float slz = b2f(ucz[row * 4096 + 2048 + d0 + dd]);
        const float yl  = b2f(y[row * 2048 + d0 + dd]);
        y[row * 2048 + d0 + dd] = __float2bfloat16(yl + slz * corr);
    }
}

// ---------------------------------------------------------------------------
extern "C" void kernel_launch(void* const* d_in, const int* in_sizes, int n_in,
                              void* d_out, int out_size, void* d_ws, size_t ws_size,
                              hipStream_t stream)
{
    char* ws = (char*)d_ws;
    const size_t MiB = 1048576;
    const size_t HMiB = 524288;

    // Layout (liveness-audited, all within proven [0, 61.8 MiB)):
    //   step:            1    2    3    4    5    6a   6b   6c   7    8    9    10
    bf16*  ucz  = (bf16*)(ws);                        // [ 0,16): conv u | silu(z)   W3 R4,6a,6c
    bf16*  dbc  = (bf16*)(ws + 16 * MiB);             // [16,16.5)                   W4 R5,6a,6c
    bf16*  xn   = (bf16*)(ws + 16 * MiB + HMiB);      // [16.5,20.5) ln1 out         W1 R2 (dead ≥5)
    bf16*  dlb  = (bf16*)(ws + 16 * MiB + HMiB);      // [16.5,24.5) delta/y inplace W5 RW6a,6c R7
    bf16*  xz   = (bf16*)(ws + 20 * MiB + HMiB);      // [20.5,36.5) in_proj out     W2 R3 (dead ≥4)
    bf16*  Pbuf = (bf16*)(ws + 24 * MiB + HMiB);      // [24.5,32.5) over dead xz    W6a R6b,6c
    float* hout = (float*)(ws + 32 * MiB + HMiB);     // [32.5,34.5) over dead xz    W6a R6b
    float* hin  = (float*)(ws + 34 * MiB + HMiB);     // [34.5,36.5) over dead xz    W6b R6c
    float* hb   = (float*)(ws);                       // [ 0, 8) over dead ucz       W7 R8,10
    bf16*  hn   = (bf16*)(ws +  8 * MiB);             // [ 8,12) over dead ucz       W8 R9
    bf16*  gb   = (bf16*)(ws + 24 * MiB + HMiB);      // [24.5,32.5) over dead Pbuf  W9 R10
    unsigned short* cvt = (unsigned short*)(ws + 37 * MiB);  // [37, 61.8)

    const float* xf     = (const float*)d_in[0];
    const float* A_logf = (const float*)d_in[9];
    const float* Dpf    = (const float*)d_in[10];

    const bf16* ln1_w      = (const bf16*)(cvt + 2097152);
    const bf16* ln1_b      = (const bf16*)(cvt + 2098176);
    const bf16* in_proj_w  = (const bf16*)(cvt + 2099200);
    const bf16* conv_w     = (const bf16*)(cvt + 6293504);
    const bf16* conv_b     = (const bf16*)(cvt + 6301696);
    const bf16* x_proj_w   = (const bf16*)(cvt + 6303744);
    const bf16* dt_proj_w  = (const bf16*)(cvt + 6500352);
    const bf16* dt_proj_b  = (const bf16*)(cvt + 6631424);
    const bf16* out_proj_w = (const bf16*)(cvt + 6668288);
    const bf16* ln2_w      = (const bf16*)(cvt + 8765440);
    const bf16* ln2_b      = (const bf16*)(cvt + 8766464);
    const bf16* mlp_w1     = (const bf16*)(cvt + 8767488);
    const bf16* mlp_b1     = (const bf16*)(cvt + 10864640);
    const bf16* mlp_w2     = (const bf16*)(cvt + 10866688);
    const bf16* mlp_b2     = (const bf16*)(cvt + 12963840);

    Ptrs ptrs;
    for (int i = 0; i < 18; ++i) ptrs.p[i] = d_in[i];
    convert_kernel<<<6332, 256, 0, stream>>>(ptrs, cvt);

    // 1. LN1
    ln_kernel<float><<<2048, 256, 0, stream>>>(xf, ln1_w, ln1_b, xn);
    // 2. in_proj (2048,4096,K=1024)
    gemm_as<128, 128, 0, false, bf16, bf16><<<dim3(32, 16), 256, 0, stream>>>(
        xn, 1024, in_proj_w, 1024, xz, 4096, nullptr, (const bf16*)nullptr, 2048, 4096, 1024);
    // 3. conv + silu + silu(z) -> ucz (xz fully dead after this)
    conv_silu_kernel<<<16384, 256, 0, stream>>>(xz, conv_w, conv_b, ucz);
    // 4. x_proj (2048,96,K=2048), A = ucz u-half (lda=4096)
    gemm_as<64, 64, 0, true, bf16, bf16><<<dim3(2, 32), 256, 0, stream>>>(
        ucz, 4096, x_proj_w, 2048, dbc, 96, nullptr, (const bf16*)nullptr, 2048, 96, 2048);
    // 5. dt_proj + softplus (2048,2048,K=64)
    gemm_as<64, 64, 2, false, bf16, bf16><<<dim3(32, 32), 256, 0, stream>>>(
        dbc, 96, dt_proj_w, 64, dlb, 2048, dt_proj_b, (const bf16*)nullptr, 2048, 2048, 64);
    // 6. selective scan (segment-parallel)
    scan_local_kernel<<<dim3(128, 2, 8), 256, 0, stream>>>(
        dlb, ucz, dbc, A_logf, Dpf, dlb, Pbuf, hout);
    scan_combine_kernel<<<256, 256, 0, stream>>>(Pbuf, A_logf, hout, hin);
    scan_fix_kernel<<<dim3(128, 2, 8), 256, 0, stream>>>(
        dlb, Pbuf, dbc, ucz, A_logf, hin);
    // 7. out_proj + residual x (fp32)
    gemm_as<64, 64, 0, false, float, float><<<dim3(16, 32), 256, 0, stream>>>(
        dlb, 2048, out_proj_w, 2048, hb, 1024, nullptr, xf, 2048, 1024, 2048);
    // 8. LN2
    ln_kernel<float><<<2048, 256, 0, stream>>>(hb, ln2_w, ln2_b, hn);
    // 9. MLP1 + gelu
    gemm_as<64, 64, 1, false, bf16, bf16><<<dim3(32, 32), 256, 0, stream>>>(
        hn, 1024, mlp_w1, 1024, gb, 2048, mlp_b1, (const bf16*)nullptr, 2048, 2048, 1024);
    // 10. MLP2 + bias + residual h -> d_out (fp32)
    gemm_as<64, 64, 0, false, float, float><<<dim3(16, 32), 256, 0, stream>>>(
        gb, 2048, mlp_w2, 2048, (float*)d_out, 1024, mlp_b2, hb, 2048, 1024, 2048);
}

// Round 10
// 370.473 us; speedup vs baseline: 1.0764x; 1.0764x over previous
//
#include <hip/hip_runtime.h>
#include <hip/hip_bf16.h>
#include <math.h>

typedef __hip_bfloat16 bf16;
typedef __attribute__((ext_vector_type(8))) short bf16x8;
typedef __attribute__((ext_vector_type(4))) float f32x4;

__device__ __forceinline__ float b2f(bf16 x) { return __bfloat162float(x); }
__device__ __forceinline__ float us2f(unsigned short u) {
    return __uint_as_float(((unsigned int)u) << 16);
}
__device__ __forceinline__ unsigned short f2us(float f) {
    bf16 t = __float2bfloat16(f);
    return *reinterpret_cast<unsigned short*>(&t);
}
__device__ __forceinline__ float scrub(float v) {
    return (v == v && fabsf(v) < 3.0e38f) ? v : 0.f;
}
__device__ __forceinline__ float to_float(float x) { return x; }
__device__ __forceinline__ float to_float(bf16 x) { return __bfloat162float(x); }
__device__ __forceinline__ void store_out(float* p, float v) { *p = v; }
__device__ __forceinline__ void store_out(bf16* p, float v) { *p = __float2bfloat16(v); }

// async global->LDS, 16 B per lane; LDS dest = wave-uniform base + lane*16.
__device__ __forceinline__ void cp16(const void* g, void* l) {
    __builtin_amdgcn_global_load_lds(
        (const __attribute__((address_space(1))) unsigned int*)g,
        (__attribute__((address_space(3))) unsigned int*)l, 16, 0, 0);
}

// ---------------------------------------------------------------------------
// Convert all 18 fp32 input tensors into one contiguous bf16 region.
// ---------------------------------------------------------------------------
struct Ptrs { const void* p[18]; };

__constant__ __device__ const long TOFF[19] = {
    0,         2097152,  2098176,  2099200,  6293504,  6301696,  6303744,
    6500352,   6631424,  6633472,  6666240,  6668288,  8765440,  8766464,
    8767488,   10864640, 10866688, 12963840, 12964864};

__global__ __launch_bounds__(256) void convert_kernel(
    Ptrs ptrs, unsigned short* __restrict__ dst)
{
    const long g = (long)blockIdx.x * 256 + threadIdx.x;
    if (g >= 1620608) return;            // 12,964,864 / 8
    const long e0 = g * 8;
    int t = 0;
    #pragma unroll
    for (int i = 1; i < 18; ++i) t += (e0 >= TOFF[i]) ? 1 : 0;
    const long local = e0 - TOFF[t];
    const float4* ps = (const float4*)((const float*)ptrs.p[t] + local);
    const float4 a = ps[0], b = ps[1];
    ushort4 o0, o1;
    o0.x = f2us(a.x); o0.y = f2us(a.y); o0.z = f2us(a.z); o0.w = f2us(a.w);
    o1.x = f2us(b.x); o1.y = f2us(b.y); o1.z = f2us(b.z); o1.w = f2us(b.w);
    *(ushort4*)(dst + e0)     = o0;
    *(ushort4*)(dst + e0 + 4) = o1;
}

// ---------------------------------------------------------------------------
// LayerNorm: one block per row of 1024, 256 threads x 4 elems.
// ---------------------------------------------------------------------------
template <typename TIN>
__global__ __launch_bounds__(256) void ln_kernel(
    const TIN* __restrict__ in, const bf16* __restrict__ gw,
    const bf16* __restrict__ gb, bf16* __restrict__ out)
{
    const int row = blockIdx.x;
    const int tid = threadIdx.x;
    float v[4];
    if constexpr (sizeof(TIN) == 2) {
        ushort4 raw = ((const ushort4*)((const unsigned short*)in + (long)row * 1024))[tid];
        v[0] = us2f(raw.x); v[1] = us2f(raw.y); v[2] = us2f(raw.z); v[3] = us2f(raw.w);
    } else {
        float4 raw = ((const float4*)((const float*)in + (long)row * 1024))[tid];
        v[0] = raw.x; v[1] = raw.y; v[2] = raw.z; v[3] = raw.w;
    }
    float s  = v[0] + v[1] + v[2] + v[3];
    float s2 = v[0]*v[0] + v[1]*v[1] + v[2]*v[2] + v[3]*v[3];
    #pragma unroll
    for (int o = 32; o > 0; o >>= 1) {
        s  += __shfl_xor(s, o);
        s2 += __shfl_xor(s2, o);
    }
    __shared__ float red[8];
    if ((tid & 63) == 0) { red[tid >> 6] = s; red[4 + (tid >> 6)] = s2; }
    __syncthreads();
    s  = red[0] + red[1] + red[2] + red[3];
    s2 = red[4] + red[5] + red[6] + red[7];
    const float mu  = s * (1.f / 1024.f);
    const float var = fmaxf(s2 * (1.f / 1024.f) - mu * mu, 0.f);
    const float rs  = rsqrtf(var + 1e-5f);
    const int c0 = tid * 4;
    ushort4 o;
    o.x = f2us((v[0] - mu) * rs * b2f(gw[c0 + 0]) + b2f(gb[c0 + 0]));
    o.y = f2us((v[1] - mu) * rs * b2f(gw[c0 + 1]) + b2f(gb[c0 + 1]));
    o.z = f2us((v[2] - mu) * rs * b2f(gw[c0 + 2]) + b2f(gb[c0 + 2]));
    o.w = f2us((v[3] - mu) * rs * b2f(gw[c0 + 3]) + b2f(gb[c0 + 3]));
    ((ushort4*)((unsigned short*)out + (long)row * 1024))[tid] = o;
}

// ---------------------------------------------------------------------------
// GEMM (m97-style): C[M,N] = act(A[M,K] @ Bw[N,K]^T + bias) + res.
// SK>1: split-K over blockIdx.z; K = slice length; C = fp32 partial slab.
// ---------------------------------------------------------------------------
template <int BM, int BN, int ACT, bool NG, int SK, typename TOUT, typename TRES>
__global__ __launch_bounds__(256) void gemm_as(
    const bf16* __restrict__ A, int lda,
    const bf16* __restrict__ Bw, int ldb,
    TOUT* __restrict__ C, int ldc,
    const bf16* __restrict__ bias,
    const TRES* __restrict__ res,
    int M, int N, int K)
{
    constexpr int AI = BM / 32;
    constexpr int BJ = BN / 32;
    __shared__ __align__(16) short As[BM * 64];
    __shared__ __align__(16) short Bs[BN * 64];
    const int tid  = threadIdx.x;
    const int lane = tid & 63;
    const int wv   = tid >> 6;
    const int m0 = blockIdx.y * BM;
    const int n0 = blockIdx.x * BN;
    if (SK > 1) {
        const int bz = blockIdx.z;
        A  += (long)bz * K;                 // k-offset within row
        Bw += (long)bz * K;
        C  += (long)bz * M * (long)ldc;     // partial slab
    }
    const int wm = (wv >> 1) * (BM / 2);
    const int wn = (wv & 1) * (BN / 2);
    const int lr = lane & 15;
    const int lq = lane >> 4;
    const int grow = lane >> 3;
    const int gcol = (lane & 7) * 8;

    if (NG) {
        const int z0 = (N - n0) * 64;
        uint4 z; z.x = z.y = z.z = z.w = 0;
        for (int s = z0 + tid * 8; s < BN * 64; s += 2048)
            *(uint4*)&Bs[s] = z;
    }

    f32x4 acc[AI][BJ] = {};

    for (int k0 = 0; k0 < K; k0 += 64) {
        #pragma unroll
        for (int g = 0; g < BM / 32; ++g) {
            const int gg = g * 4 + wv;
            cp16(A + (long)(m0 + gg * 8 + grow) * lda + k0 + gcol, &As[gg * 512]);
        }
        #pragma unroll
        for (int g = 0; g < BN / 32; ++g) {
            const int gg = g * 4 + wv;
            if (!NG || n0 + gg * 8 < N)
                cp16(Bw + (long)(n0 + gg * 8 + grow) * ldb + k0 + gcol, &Bs[gg * 512]);
        }
        __syncthreads();

        #pragma unroll
        for (int kk = 0; kk < 2; ++kk) {
            bf16x8 af[AI], bfr[BJ];
            #pragma unroll
            for (int i = 0; i < AI; ++i)
                af[i] = *(const bf16x8*)&As[(wm + i * 16 + lr) * 64 + kk * 32 + lq * 8];
            #pragma unroll
            for (int j = 0; j < BJ; ++j)
                bfr[j] = *(const bf16x8*)&Bs[(wn + j * 16 + lr) * 64 + kk * 32 + lq * 8];
            #pragma unroll
            for (int i = 0; i < AI; ++i)
                #pragma unroll
                for (int j = 0; j < BJ; ++j)
                    acc[i][j] = __builtin_amdgcn_mfma_f32_16x16x32_bf16(
                        af[i], bfr[j], acc[i][j], 0, 0, 0);
        }
        __syncthreads();
    }

    #pragma unroll
    for (int j = 0; j < BJ; ++j) {
        const int col = n0 + wn + j * 16 + lr;
        if (col >= N) continue;
        const float bv = bias ? b2f(bias[col]) : 0.f;
        #pragma unroll
        for (int i = 0; i < AI; ++i) {
            const int r0 = m0 + wm + i * 16 + lq * 4;
            #pragma unroll
            for (int r = 0; r < 4; ++r) {
                const long row = r0 + r;
                float v = acc[i][j][r] + bv;
                if (ACT == 1) v = 0.5f * v * (1.f + erff(v * 0.70710678118f));
                if (ACT == 2) v = (v > 20.f) ? v : log1pf(__expf(v));
                if (res) v += to_float(res[row * (long)ldc + col]);
                store_out(&C[row * (long)ldc + col], scrub(v));
            }
        }
    }
}

// split-K reduce: dbc[i] = bf16( sum_z part[z][i] ), i over 2048*96.
__global__ __launch_bounds__(256) void splitk_reduce_kernel(
    const float* __restrict__ part, bf16* __restrict__ out)
{
    const int i = blockIdx.x * 256 + threadIdx.x;
    if (i >= 196608) return;
    float s = 0.f;
    #pragma unroll
    for (int z = 0; z < 8; ++z) s += part[(long)z * 196608 + i];
    out[i] = __float2bfloat16(s);
}

// ---------------------------------------------------------------------------
// Depthwise causal conv (window 4) + bias + silu, PLUS silu(z) extraction.
// ---------------------------------------------------------------------------
__global__ __launch_bounds__(256) void conv_silu_kernel(
    const bf16* __restrict__ xz, const bf16* __restrict__ cw,
    const bf16* __restrict__ cb, bf16* __restrict__ ucz)
{
    const int gid = blockIdx.x * 256 + threadIdx.x;
    const int d   = gid & 2047;
    const int row = gid >> 11;
    const int t   = row & 1023;
    float acc = b2f(cb[d]);
    #pragma unroll
    for (int j = 0; j < 4; ++j) {
        const int tt = t - 3 + j;
        if (tt >= 0)
            acc += b2f(cw[d * 4 + j]) * b2f(xz[(long)(row - 3 + j) * 4096 + d]);
    }
    ucz[(long)row * 4096 + d] = __float2bfloat16(acc / (1.f + __expf(-acc)));
    const float zz = b2f(xz[(long)row * 4096 + 2048 + d]);
    ucz[(long)row * 4096 + 2048 + d] = __float2bfloat16(zz / (1.f + __expf(-zz)));
}

// ---------------------------------------------------------------------------
// Selective scan: segment-parallel.  Round-10 fixes:
//  * sP layout [dl*648 + t*20 + n]: phase-3 banks = t*20%32 (2-way, free);
//    phase-2 write banks = dl*8+n (2-way).  Was 16-way (stride 320 = 0 mod 32).
//  * XCD swizzle d0: adjacent 16-ch blocks share an XCD's L2 so 64B lines
//    split across two blocks are fetched once per XCD, not twice.
//  * B/C staged via one 64B-contiguous row read.
// ---------------------------------------------------------------------------
__device__ __forceinline__ int swizzle_d0(int bx) {
    return ((bx & 7) << 8) | ((bx >> 3) << 4);   // XCD-contiguous channel bands
}

__global__ __launch_bounds__(256) void scan_local_kernel(
    const bf16* __restrict__ delta,    // (B*L, 2048)
    const bf16* __restrict__ ucz,      // (B*L, 4096): u | silu(z)
    const bf16* __restrict__ dbc,      // (B*L, 96): dt | B | C
    const float* __restrict__ A_log,   // (2048, 16) fp32
    const float* __restrict__ Dp,      // (2048)     fp32
    bf16* __restrict__ y_local,        // aliases delta, safe
    bf16* __restrict__ Pbuf,           // (B*L, 2048) cumsum dt (bf16)
    float* __restrict__ h_out)         // (B, 8, 2048, 16)
{
    const int d0  = swizzle_d0(blockIdx.x);
    const int b   = blockIdx.y;
    const int sg  = blockIdx.z;
    const int tid = threadIdx.x;
    const int n   = tid & 15;
    const int dl  = tid >> 4;
    const int d   = d0 + dl;

    __shared__ float2         sDU[32][16];
    __shared__ float2         sBC[32][16];
    __shared__ float          sZ [32][16];
    __shared__ unsigned short sPc[32][16];
    __shared__ unsigned short sY [32][16];
    __shared__ float          sP [16 * 648];   // dl*648 + t*20 + n

    const float An = -expf(A_log[d * 16 + n]);
    const float Dd = Dp[d];
    float h = 0.f, Pc = 0.f;
    const long rowbase = (long)b * 1024 + sg * 128;

    const int wv  = tid >> 6;
    const int pdl = 4 * wv + ((tid & 63) >> 4);
    const int ptq = tid & 15;

    float rDT[2], rUV[2], rZ[2], rBC[4];
    auto load_chunk = [&](int t0c) {
        #pragma unroll
        for (int k = 0; k < 2; ++k) {
            const int i  = k * 256 + tid;
            const int tt = i >> 4, dd = i & 15;
            const long r = rowbase + t0c + tt;
            rDT[k] = b2f(delta[r * 2048 + d0 + dd]);
            rUV[k] = b2f(ucz  [r * 4096 + d0 + dd]);
            rZ[k]  = b2f(ucz  [r * 4096 + 2048 + d0 + dd]);
        }
        #pragma unroll
        for (int k = 0; k < 4; ++k) {       // B|C: 64B contiguous per row
            const int i  = k * 256 + tid;
            const int tt = i >> 5, c = i & 31;
            rBC[k] = b2f(dbc[(rowbase + t0c + tt) * 96 + 64 + c]);
        }
    };
    auto store_chunk = [&]() {
        #pragma unroll
        for (int k = 0; k < 2; ++k) {
            const int i  = k * 256 + tid;
            const int tt = i >> 4, dd = i & 15;
            sDU[tt][dd] = float2{rDT[k], rUV[k]};
            sZ[tt][dd]  = rZ[k];
        }
        #pragma unroll
        for (int k = 0; k < 4; ++k) {
            const int i  = k * 256 + tid;
            const int tt = i >> 5, c = i & 31;
            ((float*)&sBC[tt][0])[(c & 15) * 2 + (c >> 4)] = rBC[k];
        }
    };

    load_chunk(0);
    for (int t0 = 0; t0 < 128; t0 += 32) {
        store_chunk();
        __syncthreads();
        if (t0 + 32 < 128) load_chunk(t0 + 32);

        // ---- phase 2: serial recurrence (no cross-lane) ----
        #pragma unroll 4
        for (int t = 0; t < 32; ++t) {
            const float2 du = sDU[t][dl];
            const float2 bc = sBC[t][n];
            Pc += du.x;
            const float a = __expf(du.x * An);
            h = a * h + (du.x * du.y) * bc.x;
            float p = h * bc.y;
            if (n == 0) { p += du.y * Dd; sPc[t][dl] = f2us(Pc); }
            sP[dl * 648 + t * 20 + n] = p;
        }

        // ---- phase 3: wave-local n-reduction ----
        #pragma unroll
        for (int k = 0; k < 2; ++k) {
            const int t = ptq + k * 16;
            const float4* pp = (const float4*)&sP[pdl * 648 + t * 20];
            const float4 p0 = pp[0], p1 = pp[1], p2 = pp[2], p3 = pp[3];
            const float s = ((p0.x + p0.y) + (p0.z + p0.w))
                          + ((p1.x + p1.y) + (p1.z + p1.w))
                          + ((p2.x + p2.y) + (p2.z + p2.w))
                          + ((p3.x + p3.y) + (p3.z + p3.w));
            sY[t][pdl] = f2us(s * sZ[t][pdl]);
        }
        __syncthreads();

        // ---- dump (coalesced) ----
        #pragma unroll
        for (int k = 0; k < 2; ++k) {
            const int i  = k * 256 + tid;
            const int tt = i >> 4, dd = i & 15;
            const long r = rowbase + t0 + tt;
            ((unsigned short*)y_local)[r * 2048 + d0 + dd] = sY[tt][dd];
            ((unsigned short*)Pbuf)  [r * 2048 + d0 + dd] = sPc[tt][dd];
        }
        __syncthreads();
    }

    h_out[((long)(b * 8 + sg) * 2048 + d) * 16 + n] = h;
}

__global__ __launch_bounds__(256) void scan_combine_kernel(
    const bf16*  __restrict__ Pbuf,
    const float* __restrict__ A_log,
    const float* __restrict__ h_out,   // (B, 8, 32768)
    float* __restrict__ h_in)          // (B, 8, 32768)
{
    const int gid = blockIdx.x * 256 + threadIdx.x;   // 65536
    const int b  = gid >> 15;
    const int dn = gid & 32767;
    const int d  = dn >> 4;
    const float An = -expf(A_log[dn]);
    float hin = 0.f;
    h_in[(long)(b * 8) * 32768 + dn] = 0.f;
    for (int s = 0; s < 7; ++s) {
        const float Pend = us2f(((const unsigned short*)Pbuf)
                                [((long)b * 1024 + s * 128 + 127) * 2048 + d]);
        const float hout = h_out[(long)(b * 8 + s) * 32768 + dn];
        hin = hout + __expf(An * Pend) * hin;
        h_in[(long)(b * 8 + s + 1) * 32768 + dn] = hin;
    }
}

__global__ __launch_bounds__(256) void scan_fix_kernel(
    bf16* __restrict__ y,
    const bf16* __restrict__ Pbuf,
    const bf16* __restrict__ dbc,
    const bf16* __restrict__ ucz,
    const float* __restrict__ A_log,
    const float* __restrict__ h_in)
{
    const int d0  = swizzle_d0(blockIdx.x);
    const int b   = blockIdx.y;
    const int sg  = blockIdx.z;
    const int tid = threadIdx.x;
    const long rowb = (long)b * 1024 + sg * 128;

    __shared__ float sH [16][16];
    __shared__ float sAn[16][16];
    __shared__ float sCc[128][16];

    sH [tid >> 4][tid & 15] = h_in[(long)(b * 8 + sg) * 32768 + d0 * 16 + tid];
    sAn[tid >> 4][tid & 15] = -expf(A_log[d0 * 16 + tid]);
    for (int i = tid; i < 2048; i += 256)
        sCc[i >> 4][i & 15] = b2f(dbc[(rowb + (i >> 4)) * 96 + 80 + (i & 15)]);
    __syncthreads();

    const int dd = tid & 15;
    float4 An4[4], H4[4];
    #pragma unroll
    for (int j = 0; j < 4; ++j) {
        An4[j] = *(const float4*)&sAn[dd][j * 4];
        H4[j]  = *(const float4*)&sH [dd][j * 4];
    }

    #pragma unroll
    for (int k = 0; k < 8; ++k) {
        const int t = k * 16 + (tid >> 4);
        const long row = rowb + t;
        const float P = us2f(((const unsigned short*)Pbuf)[row * 2048 + d0 + dd]);
        float corr = 0.f;
        #pragma unroll
        for (int j = 0; j < 4; ++j) {
            const float4 C4 = *(const float4*)&sCc[t][j * 4];
            corr += C4.x * __expf(An4[j].x * P) * H4[j].x;
            corr += C4.y * __expf(An4[j].y * P) * H4[j].y;
            corr += C4.z * __expf(An4[j].z * P) * H4[j].z;
            corr += C4.w * __expf(An4[j].w * P) * H4[j].w;
        }
        const float slz = b2f(ucz[row * 4096 + 2048 + d0 + dd]);
        const float yl  = b2f(y[row * 2048 + d0 + dd]);
        y[row * 2048 + d0 + dd] = __float2bfloat16(yl + slz * corr);
    }
}

// ---------------------------------------------------------------------------
extern "C" void kernel_launch(void* const* d_in, const int* in_sizes, int n_in,
                              void* d_out, int out_size, void* d_ws, size_t ws_size,
                              hipStream_t stream)
{
    char* ws = (char*)d_ws;
    const size_t MiB = 1048576;
    const size_t HMiB = 524288;

    bf16*  ucz  = (bf16*)(ws);                        // [ 0,16)    W3 R4,6a,6c
    bf16*  dbc  = (bf16*)(ws + 16 * MiB);             // [16,16.5)  W4b R5,6a,6c
    bf16*  xn   = (bf16*)(ws + 16 * MiB + HMiB);      // [16.5,20.5) W1 R2
    bf16*  dlb  = (bf16*)(ws + 16 * MiB + HMiB);      // [16.5,24.5) W5 RW6 R7
    bf16*  xz   = (bf16*)(ws + 20 * MiB + HMiB);      // [20.5,36.5) W2 R3 (dead >=4)
    float* xpart= (float*)(ws + 20 * MiB + HMiB);     // [20.5,26.5) W4a R4b (over dead xz)
    bf16*  Pbuf = (bf16*)(ws + 24 * MiB + HMiB);      // [24.5,32.5) W6a R6b,6c (over dead xpart tail is fine: xpart dead after 4b)
    float* hout = (float*)(ws + 32 * MiB + HMiB);     // [32.5,34.5) W6a R6b
    float* hin  = (float*)(ws + 34 * MiB + HMiB);     // [34.5,36.5) W6b R6c
    float* hb   = (float*)(ws);                       // [ 0, 8)  W7 R8,10 (over dead ucz)
    bf16*  hn   = (bf16*)(ws +  8 * MiB);             // [ 8,12)  W8 R9
    bf16*  gb   = (bf16*)(ws + 24 * MiB + HMiB);      // [24.5,32.5) W9 R10 (over dead Pbuf)
    unsigned short* cvt = (unsigned short*)(ws + 37 * MiB);

    const float* xf     = (const float*)d_in[0];
    const float* A_logf = (const float*)d_in[9];
    const float* Dpf    = (const float*)d_in[10];

    const bf16* ln1_w      = (const bf16*)(cvt + 2097152);
    const bf16* ln1_b      = (const bf16*)(cvt + 2098176);
    const bf16* in_proj_w  = (const bf16*)(cvt + 2099200);
    const bf16* conv_w     = (const bf16*)(cvt + 6293504);
    const bf16* conv_b     = (const bf16*)(cvt + 6301696);
    const bf16* x_proj_w   = (const bf16*)(cvt + 6303744);
    const bf16* dt_proj_w  = (const bf16*)(cvt + 6500352);
    const bf16* dt_proj_b  = (const bf16*)(cvt + 6631424);
    const bf16* out_proj_w = (const bf16*)(cvt + 6668288);
    const bf16* ln2_w      = (const bf16*)(cvt + 8765440);
    const bf16* ln2_b      = (const bf16*)(cvt + 8766464);
    const bf16* mlp_w1     = (const bf16*)(cvt + 8767488);
    const bf16* mlp_b1     = (const bf16*)(cvt + 10864640);
    const bf16* mlp_w2     = (const bf16*)(cvt + 10866688);
    const bf16* mlp_b2     = (const bf16*)(cvt + 12963840);

    Ptrs ptrs;
    for (int i = 0; i < 18; ++i) ptrs.p[i] = d_in[i];
    convert_kernel<<<6332, 256, 0, stream>>>(ptrs, cvt);

    // 1. LN1
    ln_kernel<float><<<2048, 256, 0, stream>>>(xf, ln1_w, ln1_b, xn);
    // 2. in_proj (2048,4096,K=1024)  128x128, 512 blocks
    gemm_as<128, 128, 0, false, 1, bf16, bf16><<<dim3(32, 16), 256, 0, stream>>>(
        xn, 1024, in_proj_w, 1024, xz, 4096, nullptr, (const bf16*)nullptr, 2048, 4096, 1024);
    // 3. conv + silu + silu(z) -> ucz
    conv_silu_kernel<<<16384, 256, 0, stream>>>(xz, conv_w, conv_b, ucz);
    // 4a. x_proj split-K=8 -> fp32 partials (512 blocks)
    gemm_as<64, 64, 0, true, 8, float, bf16><<<dim3(2, 32, 8), 256, 0, stream>>>(
        ucz, 4096, x_proj_w, 2048, xpart, 96, nullptr, (const bf16*)nullptr, 2048, 96, 256);
    // 4b. reduce partials -> dbc
    splitk_reduce_kernel<<<768, 256, 0, stream>>>(xpart, dbc);
    // 5. dt_proj + softplus (2048,2048,K=64)  128x64, 512 blocks
    gemm_as<128, 64, 2, false, 1, bf16, bf16><<<dim3(32, 16), 256, 0, stream>>>(
        dbc, 96, dt_proj_w, 64, dlb, 2048, dt_proj_b, (const bf16*)nullptr, 2048, 2048, 64);
    // 6. selective scan (segment-parallel)
    scan_local_kernel<<<dim3(128, 2, 8), 256, 0, stream>>>(
        dlb, ucz, dbc, A_logf, Dpf, dlb, Pbuf, hout);
    scan_combine_kernel<<<256, 256, 0, stream>>>(Pbuf, A_logf, hout, hin);
    scan_fix_kernel<<<dim3(128, 2, 8), 256, 0, stream>>>(
        dlb, Pbuf, dbc, ucz, A_logf, hin);
    // 7. out_proj + residual x (fp32)  64x64, 512 blocks
    gemm_as<64, 64, 0, false, 1, float, float><<<dim3(16, 32), 256, 0, stream>>>(
        dlb, 2048, out_proj_w, 2048, hb, 1024, nullptr, xf, 2048, 1024, 2048);
    // 8. LN2
    ln_kernel<float><<<2048, 256, 0, stream>>>(hb, ln2_w, ln2_b, hn);
    // 9. MLP1 + gelu (2048,2048,K=1024)  128x64, 512 blocks
    gemm_as<128, 64, 1, false, 1, bf16, bf16><<<dim3(32, 16), 256, 0, stream>>>(
        hn, 1024, mlp_w1, 1024, gb, 2048, mlp_b1, (const bf16*)nullptr, 2048, 2048, 1024);
    // 10. MLP2 + bias + residual h -> d_out (fp32)  64x64, 512 blocks
    gemm_as<64, 64, 0, false, 1, float, float><<<dim3(16, 32), 256, 0, stream>>>(
        gb, 2048, mlp_w2, 2048, (float*)d_out, 1024, mlp_b2, hb, 2048, 1024, 2048);
}

// Round 11
// 364.096 us; speedup vs baseline: 1.0953x; 1.0175x over previous
//
#include <hip/hip_runtime.h>
#include <hip/hip_bf16.h>
#include <math.h>

typedef __hip_bfloat16 bf16;
typedef __attribute__((ext_vector_type(8))) short bf16x8;
typedef __attribute__((ext_vector_type(4))) float f32x4;

__device__ __forceinline__ float b2f(bf16 x) { return __bfloat162float(x); }
__device__ __forceinline__ float us2f(unsigned short u) {
    return __uint_as_float(((unsigned int)u) << 16);
}
__device__ __forceinline__ unsigned short f2us(float f) {
    bf16 t = __float2bfloat16(f);
    return *reinterpret_cast<unsigned short*>(&t);
}
__device__ __forceinline__ float scrub(float v) {
    return (v == v && fabsf(v) < 3.0e38f) ? v : 0.f;
}
__device__ __forceinline__ float to_float(float x) { return x; }
__device__ __forceinline__ float to_float(bf16 x) { return __bfloat162float(x); }
__device__ __forceinline__ void store_out(float* p, float v) { *p = v; }
__device__ __forceinline__ void store_out(bf16* p, float v) { *p = __float2bfloat16(v); }

__device__ __forceinline__ void ld8(const bf16* p, float* f) {
    const ushort4 a = ((const ushort4*)p)[0];
    const ushort4 b = ((const ushort4*)p)[1];
    f[0]=us2f(a.x); f[1]=us2f(a.y); f[2]=us2f(a.z); f[3]=us2f(a.w);
    f[4]=us2f(b.x); f[5]=us2f(b.y); f[6]=us2f(b.z); f[7]=us2f(b.w);
}

// async global->LDS, 16 B per lane; LDS dest = wave-uniform base + lane*16.
__device__ __forceinline__ void cp16(const void* g, void* l) {
    __builtin_amdgcn_global_load_lds(
        (const __attribute__((address_space(1))) unsigned int*)g,
        (__attribute__((address_space(3))) unsigned int*)l, 16, 0, 0);
}

// ---------------------------------------------------------------------------
// Convert all 18 fp32 input tensors into one contiguous bf16 region.
// ---------------------------------------------------------------------------
struct Ptrs { const void* p[18]; };

__constant__ __device__ const long TOFF[19] = {
    0,         2097152,  2098176,  2099200,  6293504,  6301696,  6303744,
    6500352,   6631424,  6633472,  6666240,  6668288,  8765440,  8766464,
    8767488,   10864640, 10866688, 12963840, 12964864};

__global__ __launch_bounds__(256) void convert_kernel(
    Ptrs ptrs, unsigned short* __restrict__ dst)
{
    const long g = (long)blockIdx.x * 256 + threadIdx.x;
    if (g >= 1620608) return;            // 12,964,864 / 8
    const long e0 = g * 8;
    int t = 0;
    #pragma unroll
    for (int i = 1; i < 18; ++i) t += (e0 >= TOFF[i]) ? 1 : 0;
    const long local = e0 - TOFF[t];
    const float4* ps = (const float4*)((const float*)ptrs.p[t] + local);
    const float4 a = ps[0], b = ps[1];
    ushort4 o0, o1;
    o0.x = f2us(a.x); o0.y = f2us(a.y); o0.z = f2us(a.z); o0.w = f2us(a.w);
    o1.x = f2us(b.x); o1.y = f2us(b.y); o1.z = f2us(b.z); o1.w = f2us(b.w);
    *(ushort4*)(dst + e0)     = o0;
    *(ushort4*)(dst + e0 + 4) = o1;
}

// ---------------------------------------------------------------------------
// LayerNorm: one block per row of 1024, 256 threads x 4 elems.
// ---------------------------------------------------------------------------
template <typename TIN>
__global__ __launch_bounds__(256) void ln_kernel(
    const TIN* __restrict__ in, const bf16* __restrict__ gw,
    const bf16* __restrict__ gb, bf16* __restrict__ out)
{
    const int row = blockIdx.x;
    const int tid = threadIdx.x;
    float v[4];
    if constexpr (sizeof(TIN) == 2) {
        ushort4 raw = ((const ushort4*)((const unsigned short*)in + (long)row * 1024))[tid];
        v[0] = us2f(raw.x); v[1] = us2f(raw.y); v[2] = us2f(raw.z); v[3] = us2f(raw.w);
    } else {
        float4 raw = ((const float4*)((const float*)in + (long)row * 1024))[tid];
        v[0] = raw.x; v[1] = raw.y; v[2] = raw.z; v[3] = raw.w;
    }
    float s  = v[0] + v[1] + v[2] + v[3];
    float s2 = v[0]*v[0] + v[1]*v[1] + v[2]*v[2] + v[3]*v[3];
    #pragma unroll
    for (int o = 32; o > 0; o >>= 1) {
        s  += __shfl_xor(s, o);
        s2 += __shfl_xor(s2, o);
    }
    __shared__ float red[8];
    if ((tid & 63) == 0) { red[tid >> 6] = s; red[4 + (tid >> 6)] = s2; }
    __syncthreads();
    s  = red[0] + red[1] + red[2] + red[3];
    s2 = red[4] + red[5] + red[6] + red[7];
    const float mu  = s * (1.f / 1024.f);
    const float var = fmaxf(s2 * (1.f / 1024.f) - mu * mu, 0.f);
    const float rs  = rsqrtf(var + 1e-5f);
    const int c0 = tid * 4;
    ushort4 o;
    o.x = f2us((v[0] - mu) * rs * b2f(gw[c0 + 0]) + b2f(gb[c0 + 0]));
    o.y = f2us((v[1] - mu) * rs * b2f(gw[c0 + 1]) + b2f(gb[c0 + 1]));
    o.z = f2us((v[2] - mu) * rs * b2f(gw[c0 + 2]) + b2f(gb[c0 + 2]));
    o.w = f2us((v[3] - mu) * rs * b2f(gw[c0 + 3]) + b2f(gb[c0 + 3]));
    ((ushort4*)((unsigned short*)out + (long)row * 1024))[tid] = o;
}

// ---------------------------------------------------------------------------
// GEMM (m97-style): C[M,N] = act(A[M,K] @ Bw[N,K]^T + bias) + res.
// SK>1: split-K over blockIdx.z; K = slice length; C = fp32 partial slab.
// ---------------------------------------------------------------------------
template <int BM, int BN, int ACT, bool NG, int SK, typename TOUT, typename TRES>
__global__ __launch_bounds__(256) void gemm_as(
    const bf16* __restrict__ A, int lda,
    const bf16* __restrict__ Bw, int ldb,
    TOUT* __restrict__ C, int ldc,
    const bf16* __restrict__ bias,
    const TRES* __restrict__ res,
    int M, int N, int K)
{
    constexpr int AI = BM / 32;
    constexpr int BJ = BN / 32;
    __shared__ __align__(16) short As[BM * 64];
    __shared__ __align__(16) short Bs[BN * 64];
    const int tid  = threadIdx.x;
    const int lane = tid & 63;
    const int wv   = tid >> 6;
    const int m0 = blockIdx.y * BM;
    const int n0 = blockIdx.x * BN;
    if (SK > 1) {
        const int bz = blockIdx.z;
        A  += (long)bz * K;
        Bw += (long)bz * K;
        C  += (long)bz * M * (long)ldc;
    }
    const int wm = (wv >> 1) * (BM / 2);
    const int wn = (wv & 1) * (BN / 2);
    const int lr = lane & 15;
    const int lq = lane >> 4;
    const int grow = lane >> 3;
    const int gcol = (lane & 7) * 8;

    if (NG) {
        const int z0 = (N - n0) * 64;
        uint4 z; z.x = z.y = z.z = z.w = 0;
        for (int s = z0 + tid * 8; s < BN * 64; s += 2048)
            *(uint4*)&Bs[s] = z;
    }

    f32x4 acc[AI][BJ] = {};

    for (int k0 = 0; k0 < K; k0 += 64) {
        #pragma unroll
        for (int g = 0; g < BM / 32; ++g) {
            const int gg = g * 4 + wv;
            cp16(A + (long)(m0 + gg * 8 + grow) * lda + k0 + gcol, &As[gg * 512]);
        }
        #pragma unroll
        for (int g = 0; g < BN / 32; ++g) {
            const int gg = g * 4 + wv;
            if (!NG || n0 + gg * 8 < N)
                cp16(Bw + (long)(n0 + gg * 8 + grow) * ldb + k0 + gcol, &Bs[gg * 512]);
        }
        __syncthreads();

        #pragma unroll
        for (int kk = 0; kk < 2; ++kk) {
            bf16x8 af[AI], bfr[BJ];
            #pragma unroll
            for (int i = 0; i < AI; ++i)
                af[i] = *(const bf16x8*)&As[(wm + i * 16 + lr) * 64 + kk * 32 + lq * 8];
            #pragma unroll
            for (int j = 0; j < BJ; ++j)
                bfr[j] = *(const bf16x8*)&Bs[(wn + j * 16 + lr) * 64 + kk * 32 + lq * 8];
            #pragma unroll
            for (int i = 0; i < AI; ++i)
                #pragma unroll
                for (int j = 0; j < BJ; ++j)
                    acc[i][j] = __builtin_amdgcn_mfma_f32_16x16x32_bf16(
                        af[i], bfr[j], acc[i][j], 0, 0, 0);
        }
        __syncthreads();
    }

    #pragma unroll
    for (int j = 0; j < BJ; ++j) {
        const int col = n0 + wn + j * 16 + lr;
        if (col >= N) continue;
        const float bv = bias ? b2f(bias[col]) : 0.f;
        #pragma unroll
        for (int i = 0; i < AI; ++i) {
            const int r0 = m0 + wm + i * 16 + lq * 4;
            #pragma unroll
            for (int r = 0; r < 4; ++r) {
                const long row = r0 + r;
                float v = acc[i][j][r] + bv;
                if (ACT == 1) v = 0.5f * v * (1.f + erff(v * 0.70710678118f));
                if (ACT == 2) v = (v > 20.f) ? v : log1pf(__expf(v));
                if (res) v += to_float(res[row * (long)ldc + col]);
                store_out(&C[row * (long)ldc + col], scrub(v));
            }
        }
    }
}

// split-K reduce: dbc[i] = bf16( sum_z part[z][i] ), i over 2048*96.
__global__ __launch_bounds__(256) void splitk_reduce_kernel(
    const float* __restrict__ part, bf16* __restrict__ out)
{
    const int i = blockIdx.x * 256 + threadIdx.x;
    if (i >= 196608) return;
    float s = 0.f;
    #pragma unroll
    for (int z = 0; z < 8; ++z) s += part[(long)z * 196608 + i];
    out[i] = __float2bfloat16(s);
}

// ---------------------------------------------------------------------------
// Depthwise causal conv (window 4) + bias + silu + silu(z), vectorized x8.
// ---------------------------------------------------------------------------
__global__ __launch_bounds__(256) void conv_silu_kernel(
    const bf16* __restrict__ xz, const bf16* __restrict__ cw,
    const bf16* __restrict__ cb, bf16* __restrict__ ucz)
{
    const int gid = blockIdx.x * 256 + threadIdx.x;   // 2048 rows x 256 groups
    const int row = gid >> 8;
    const int t   = row & 1023;
    const int d   = (gid & 255) * 8;

    float w[32];                       // w[k*4+j] = cw[(d+k)*4 + j]
    ld8(cw + d * 4,      w);
    ld8(cw + d * 4 + 8,  w + 8);
    ld8(cw + d * 4 + 16, w + 16);
    ld8(cw + d * 4 + 24, w + 24);

    float acc[8];
    ld8(cb + d, acc);
    #pragma unroll
    for (int j = 0; j < 4; ++j) {
        const int tt = t - 3 + j;
        if (tt >= 0) {
            float u[8];
            ld8(xz + (long)(row - 3 + j) * 4096 + d, u);
            #pragma unroll
            for (int k = 0; k < 8; ++k) acc[k] += w[k * 4 + j] * u[k];
        }
    }
    ushort4 o0, o1;
    unsigned short* po = (unsigned short*)&o0;
    #pragma unroll
    for (int k = 0; k < 8; ++k) {
        const float v = acc[k] / (1.f + __expf(-acc[k]));
        ((unsigned short*)&o0)[k & 3 | ((k >> 2) << 31)] = 0;  // placate nothing
        if (k < 4) ((unsigned short*)&o0)[k] = f2us(v);
        else       ((unsigned short*)&o1)[k - 4] = f2us(v);
    }
    (void)po;
    ((ushort4*)(ucz + (long)row * 4096 + d))[0] = o0;
    ((ushort4*)(ucz + (long)row * 4096 + d))[1] = o1;

    float z8[8];
    ld8(xz + (long)row * 4096 + 2048 + d, z8);
    #pragma unroll
    for (int k = 0; k < 8; ++k) {
        const float v = z8[k] / (1.f + __expf(-z8[k]));
        if (k < 4) ((unsigned short*)&o0)[k] = f2us(v);
        else       ((unsigned short*)&o1)[k - 4] = f2us(v);
    }
    ((ushort4*)(ucz + (long)row * 4096 + 2048 + d))[0] = o0;
    ((ushort4*)(ucz + (long)row * 4096 + 2048 + d))[1] = o1;
}

// ---------------------------------------------------------------------------
// Selective scan: 32 segments x 32 steps (segment-parallel, grid 8192).
// sP halved (per-16-t interleave of phase2/3, wave-local) -> 33.8 KB LDS
// -> 4 blocks/CU.  H buffer: combine rewrites h_in over h_out in place.
// ---------------------------------------------------------------------------
__device__ __forceinline__ int swizzle_d0(int bx) {
    return ((bx & 7) << 8) | ((bx >> 3) << 4);   // XCD-contiguous channel bands
}

__global__ __launch_bounds__(256) void scan_local_kernel(
    const bf16* __restrict__ delta,    // (B*L, 2048)
    const bf16* __restrict__ ucz,      // (B*L, 4096): u | silu(z)
    const bf16* __restrict__ dbc,      // (B*L, 96): dt | B | C
    const float* __restrict__ A_log,   // (2048, 16) fp32
    const float* __restrict__ Dp,      // (2048)     fp32
    bf16* __restrict__ y_local,        // aliases delta, safe
    bf16* __restrict__ Pbuf,           // (B*L, 2048) cumsum dt (bf16)
    bf16* __restrict__ H)              // (B, 32, 2048, 16) local end-state
{
    const int d0  = swizzle_d0(blockIdx.x);
    const int b   = blockIdx.y;
    const int sg  = blockIdx.z;        // 0..31
    const int tid = threadIdx.x;
    const int n   = tid & 15;
    const int dl  = tid >> 4;
    const int d   = d0 + dl;

    __shared__ float2         sDU[32][16];
    __shared__ float2         sBC[32][16];
    __shared__ float          sZ [32][16];
    __shared__ unsigned short sPc[32][16];
    __shared__ unsigned short sY [32][16];
    __shared__ float          sP [16 * 336];   // dl*336 + tl*20 + n (tl<16)

    const float An = -expf(A_log[d * 16 + n]);
    const float Dd = Dp[d];
    const long rowbase = (long)b * 1024 + sg * 32;

    const int wv  = tid >> 6;
    const int pdl = 4 * wv + ((tid & 63) >> 4);
    const int ptq = tid & 15;

    // ---- staging: 32 t directly to LDS ----
    #pragma unroll
    for (int k = 0; k < 2; ++k) {
        const int i  = k * 256 + tid;
        const int tt = i >> 4, dd = i & 15;
        const long r = rowbase + tt;
        sDU[tt][dd] = float2{b2f(delta[r * 2048 + d0 + dd]),
                             b2f(ucz  [r * 4096 + d0 + dd])};
        sZ[tt][dd]  = b2f(ucz[r * 4096 + 2048 + d0 + dd]);
    }
    #pragma unroll
    for (int k = 0; k < 4; ++k) {       // B|C: 64B contiguous per row
        const int i  = k * 256 + tid;
        const int tt = i >> 5, c = i & 31;
        ((float*)&sBC[tt][0])[(c & 15) * 2 + (c >> 4)] =
            b2f(dbc[(rowbase + tt) * 96 + 64 + c]);
    }
    __syncthreads();

    // ---- recurrence, interleaved per 16-t half (wave-local sP) ----
    float h = 0.f, Pc = 0.f;
    #pragma unroll
    for (int half = 0; half < 2; ++half) {
        #pragma unroll 4
        for (int tl = 0; tl < 16; ++tl) {
            const int t = half * 16 + tl;
            const float2 du = sDU[t][dl];
            const float2 bc = sBC[t][n];
            Pc += du.x;
            const float a = __expf(du.x * An);
            h = a * h + (du.x * du.y) * bc.x;
            float p = h * bc.y;
            if (n == 0) { p += du.y * Dd; sPc[t][dl] = f2us(Pc); }
            sP[dl * 336 + tl * 20 + n] = p;
        }
        {   // wave-local n-reduction for this half
            const int t = half * 16 + ptq;
            const float4* pp = (const float4*)&sP[pdl * 336 + ptq * 20];
            const float4 p0 = pp[0], p1 = pp[1], p2 = pp[2], p3 = pp[3];
            const float s = ((p0.x + p0.y) + (p0.z + p0.w))
                          + ((p1.x + p1.y) + (p1.z + p1.w))
                          + ((p2.x + p2.y) + (p2.z + p2.w))
                          + ((p3.x + p3.y) + (p3.z + p3.w));
            sY[t][pdl] = f2us(s * sZ[t][pdl]);
        }
    }
    __syncthreads();

    // ---- dump (coalesced) ----
    #pragma unroll
    for (int k = 0; k < 2; ++k) {
        const int i  = k * 256 + tid;
        const int tt = i >> 4, dd = i & 15;
        const long r = rowbase + tt;
        ((unsigned short*)y_local)[r * 2048 + d0 + dd] = sY[tt][dd];
        ((unsigned short*)Pbuf)  [r * 2048 + d0 + dd] = sPc[tt][dd];
    }

    H[((long)(b * 32 + sg) * 2048 + d) * 16 + n] = __float2bfloat16(h);
}

// In-place: H[s] = h_in(s)  (was h_out(s)); chain in fp32 registers.
__global__ __launch_bounds__(256) void scan_combine_kernel(
    const bf16*  __restrict__ Pbuf,
    const float* __restrict__ A_log,
    bf16* __restrict__ H)              // (B, 32, 32768)
{
    const int gid = blockIdx.x * 256 + threadIdx.x;   // 65536
    const int b  = gid >> 15;
    const int dn = gid & 32767;
    const int d  = dn >> 4;
    const float An = -expf(A_log[dn]);
    float hin = 0.f;
    for (int s = 0; s < 32; ++s) {
        const long idx = (long)(b * 32 + s) * 32768 + dn;
        const float hout = b2f(H[idx]);           // read before overwrite
        H[idx] = __float2bfloat16(hin);           // input state for segment s
        const float Pend = b2f(Pbuf[((long)b * 1024 + s * 32 + 31) * 2048 + d]);
        hin = hout + __expf(An * Pend) * hin;
    }
}

__global__ __launch_bounds__(256) void scan_fix_kernel(
    bf16* __restrict__ y,
    const bf16* __restrict__ Pbuf,
    const bf16* __restrict__ dbc,
    const bf16* __restrict__ ucz,
    const float* __restrict__ A_log,
    const bf16* __restrict__ H)        // h_in per segment
{
    const int d0  = swizzle_d0(blockIdx.x);
    const int b   = blockIdx.y;
    const int sg  = blockIdx.z;        // 0..31
    const int tid = threadIdx.x;
    const long rowb = (long)b * 1024 + sg * 32;

    __shared__ float sH [16][16];
    __shared__ float sAn[16][16];
    __shared__ float sCc[32][16];

    sH [tid >> 4][tid & 15] = b2f(H[(long)(b * 32 + sg) * 32768 + d0 * 16 + tid]);
    sAn[tid >> 4][tid & 15] = -expf(A_log[d0 * 16 + tid]);
    for (int i = tid; i < 512; i += 256)
        sCc[i >> 4][i & 15] = b2f(dbc[(rowb + (i >> 4)) * 96 + 80 + (i & 15)]);
    __syncthreads();

    const int dd = tid & 15;
    float4 An4[4], H4[4];
    #pragma unroll
    for (int j = 0; j < 4; ++j) {
        An4[j] = *(const float4*)&sAn[dd][j * 4];
        H4[j]  = *(const float4*)&sH [dd][j * 4];
    }

    #pragma unroll
    for (int k = 0; k < 2; ++k) {
        const int t = k * 16 + (tid >> 4);
        const long row = rowb + t;
        const float P = us2f(((const unsigned short*)Pbuf)[row * 2048 + d0 + dd]);
        float corr = 0.f;
        #pragma unroll
        for (int j = 0; j < 4; ++j) {
            const float4 C4 = *(const float4*)&sCc[t][j * 4];
            corr += C4.x * __expf(An4[j].x * P) * H4[j].x;
            corr += C4.y * __expf(An4[j].y * P) * H4[j].y;
            corr += C4.z * __expf(An4[j].z * P) * H4[j].z;
            corr += C4.w * __expf(An4[j].w * P) * H4[j].w;
        }
        const float slz = b2f(ucz[row * 4096 + 2048 + d0 + dd]);
        const float yl  = b2f(y[row * 2048 + d0 + dd]);
        y[row * 2048 + d0 + dd] = __float2bfloat16(yl + slz * corr);
    }
}

// ---------------------------------------------------------------------------
extern "C" void kernel_launch(void* const* d_in, const int* in_sizes, int n_in,
                              void* d_out, int out_size, void* d_ws, size_t ws_size,
                              hipStream_t stream)
{
    char* ws = (char*)d_ws;
    const size_t MiB = 1048576;
    const size_t HMiB = 524288;

    // Liveness-audited layout:
    bf16*  ucz  = (bf16*)(ws);                        // [ 0,16)    W3 R4,6a,6c
    bf16*  dbc  = (bf16*)(ws + 16 * MiB);             // [16,16.5)  W4b R5,6a,6c
    bf16*  xn   = (bf16*)(ws + 16 * MiB + HMiB);      // [16.5,20.5) W1 R2 (dead >=3)
    bf16*  dlb  = (bf16*)(ws + 16 * MiB + HMiB);      // [16.5,24.5) W5 RW6a,6c R7
    bf16*  xz   = (bf16*)(ws + 20 * MiB + HMiB);      // [20.5,36.5) W2 R3 (dead >=4a-done)
    float* xpart= (float*)(ws + 20 * MiB + HMiB);     // [20.5,26.5) W4a R4b (dead >=5)
    bf16*  Pbuf = (bf16*)(ws + 24 * MiB + HMiB);      // [24.5,32.5) W6a R6b,6c (over dead xpart/xz)
    bf16*  Hbuf = (bf16*)(ws + 32 * MiB + HMiB);      // [32.5,36.5) W6a RW6b R6c (over dead xz)
    float* hb   = (float*)(ws);                       // [ 0, 8)  W7 R8,10 (over dead ucz)
    bf16*  hn   = (bf16*)(ws +  8 * MiB);             // [ 8,12)  W8 R9
    bf16*  gb   = (bf16*)(ws + 24 * MiB + HMiB);      // [24.5,32.5) W9 R10 (over dead Pbuf)
    unsigned short* cvt = (unsigned short*)(ws + 37 * MiB);

    const float* xf     = (const float*)d_in[0];
    const float* A_logf = (const float*)d_in[9];
    const float* Dpf    = (const float*)d_in[10];

    const bf16* ln1_w      = (const bf16*)(cvt + 2097152);
    const bf16* ln1_b      = (const bf16*)(cvt + 2098176);
    const bf16* in_proj_w  = (const bf16*)(cvt + 2099200);
    const bf16* conv_w     = (const bf16*)(cvt + 6293504);
    const bf16* conv_b     = (const bf16*)(cvt + 6301696);
    const bf16* x_proj_w   = (const bf16*)(cvt + 6303744);
    const bf16* dt_proj_w  = (const bf16*)(cvt + 6500352);
    const bf16* dt_proj_b  = (const bf16*)(cvt + 6631424);
    const bf16* out_proj_w = (const bf16*)(cvt + 6668288);
    const bf16* ln2_w      = (const bf16*)(cvt + 8765440);
    const bf16* ln2_b      = (const bf16*)(cvt + 8766464);
    const bf16* mlp_w1     = (const bf16*)(cvt + 8767488);
    const bf16* mlp_b1     = (const bf16*)(cvt + 10864640);
    const bf16* mlp_w2     = (const bf16*)(cvt + 10866688);
    const bf16* mlp_b2     = (const bf16*)(cvt + 12963840);

    Ptrs ptrs;
    for (int i = 0; i < 18; ++i) ptrs.p[i] = d_in[i];
    convert_kernel<<<6332, 256, 0, stream>>>(ptrs, cvt);

    // 1. LN1
    ln_kernel<float><<<2048, 256, 0, stream>>>(xf, ln1_w, ln1_b, xn);
    // 2. in_proj (2048,4096,K=1024)
    gemm_as<128, 128, 0, false, 1, bf16, bf16><<<dim3(32, 16), 256, 0, stream>>>(
        xn, 1024, in_proj_w, 1024, xz, 4096, nullptr, (const bf16*)nullptr, 2048, 4096, 1024);
    // 3. conv + silu + silu(z) -> ucz  (vectorized x8)
    conv_silu_kernel<<<2048, 256, 0, stream>>>(xz, conv_w, conv_b, ucz);
    // 4a. x_proj split-K=8 -> fp32 partials
    gemm_as<64, 64, 0, true, 8, float, bf16><<<dim3(2, 32, 8), 256, 0, stream>>>(
        ucz, 4096, x_proj_w, 2048, xpart, 96, nullptr, (const bf16*)nullptr, 2048, 96, 256);
    // 4b. reduce partials -> dbc
    splitk_reduce_kernel<<<768, 256, 0, stream>>>(xpart, dbc);
    // 5. dt_proj + softplus (2048,2048,K=64)
    gemm_as<128, 64, 2, false, 1, bf16, bf16><<<dim3(32, 16), 256, 0, stream>>>(
        dbc, 96, dt_proj_w, 64, dlb, 2048, dt_proj_b, (const bf16*)nullptr, 2048, 2048, 64);
    // 6. selective scan: 32 segments
    scan_local_kernel<<<dim3(128, 2, 32), 256, 0, stream>>>(
        dlb, ucz, dbc, A_logf, Dpf, dlb, Pbuf, Hbuf);
    scan_combine_kernel<<<256, 256, 0, stream>>>(Pbuf, A_logf, Hbuf);
    scan_fix_kernel<<<dim3(128, 2, 32), 256, 0, stream>>>(
        dlb, Pbuf, dbc, ucz, A_logf, Hbuf);
    // 7. out_proj + residual x (fp32)
    gemm_as<64, 64, 0, false, 1, float, float><<<dim3(16, 32), 256, 0, stream>>>(
        dlb, 2048, out_proj_w, 2048, hb, 1024, nullptr, xf, 2048, 1024, 2048);
    // 8. LN2
    ln_kernel<float><<<2048, 256, 0, stream>>>(hb, ln2_w, ln2_b, hn);
    // 9. MLP1 + gelu
    gemm_as<128, 64, 1, false, 1, bf16, bf16><<<dim3(32, 16), 256, 0, stream>>>(
        hn, 1024, mlp_w1, 1024, gb, 2048, mlp_b1, (const bf16*)nullptr, 2048, 2048, 1024);
    // 10. MLP2 + bias + residual h -> d_out (fp32)
    gemm_as<64, 64, 0, false, 1, float, float><<<dim3(16, 32), 256, 0, stream>>>(
        gb, 2048, mlp_w2, 2048, (float*)d_out, 1024, mlp_b2, hb, 2048, 1024, 2048);
}